// Round 1
// baseline (5613.440 us; speedup 1.0000x reference)
//
#include <hip/hip_runtime.h>
#include <math.h>

#define NT 256

// lidx(k): degree-band index l/2 for coefficient k (bands at k = 0,1,6,15,28)
__device__ __forceinline__ int lidxf(int k) {
  return (k < 1) ? 0 : (k < 6) ? 1 : (k < 15) ? 2 : (k < 28) ? 3 : 4;
}
// scale = sqrt(pi/(2l+1)), l = 2j
__device__ __forceinline__ float scale_from_j(int j) {
  float s = 1.7724539f;            // sqrt(pi/1)
  s = (j == 1) ? 0.79266548f : s;  // sqrt(pi/5)
  s = (j == 2) ? 0.59081795f : s;  // sqrt(pi/9)
  s = (j == 3) ? 0.49159026f : s;  // sqrt(pi/13)
  s = (j == 4) ? 0.42988324f : s;  // sqrt(pi/17)
  return s;
}

// LDS layout (float offsets):
//  WI: isft^T, [k=0..44][p stride 92], cols p>=90 zeroed  (4140)
//  WS: sft^T,  [p=0..91][k stride 48], k>=45 & p>=90 zero (4416)
//  AB: arena:  x_in rows | y rows | sig rows (max 7552 @ layer 4)
#define WIB 0
#define WSB 4140
#define AB  8556
#define LDS_FLOATS 16108   // 64432 bytes -> 2 blocks/CU

#define LD4(off) (*(const float4*)&L[(off)])
#define ST4(off, v) (*(float4*)&L[(off)] = (v))

__global__ __launch_bounds__(NT, 2)
void scnn_all(const float* __restrict__ xin, const float* __restrict__ sft,
              const float* __restrict__ isft,
              const float* __restrict__ w1c, const float* __restrict__ w2c,
              const float* __restrict__ w3c, const float* __restrict__ w4c,
              const float* __restrict__ w5c, const float* __restrict__ w6c,
              float* __restrict__ out, int nbatch) {
  __shared__ float L[LDS_FLOATS];
  const int tid = threadIdx.x;
  const int b = blockIdx.x;

  // ---- stage weights into LDS (coalesced global reads, scattered LDS writes)
  for (int i = tid; i < 90 * 45; i += NT) {  // WI[k][p] = isft[p][k]
    int p = i / 45, k = i - p * 45;
    L[WIB + k * 92 + p] = isft[i];
  }
  for (int i = tid; i < 90; i += NT) {       // WI pad cols p=90,91
    int k = i >> 1;
    L[WIB + k * 92 + 90 + (i & 1)] = 0.f;
  }
  for (int i = tid; i < 45 * 90; i += NT) {  // WS[p][k] = sft[k][p]
    int k = i / 90, p = i - k * 90;
    L[WSB + p * 48 + k] = sft[i];
  }
  for (int i = tid; i < 92 * 3; i += NT) {   // WS pad k=45..47
    int p = i / 3;
    L[WSB + p * 48 + 45 + (i - p * 3)] = 0.f;
  }
  for (int i = tid; i < 2 * 48; i += NT) {   // WS pad rows p=90,91
    L[WSB + 90 * 48 + i] = 0.f;
  }
  for (int i = tid; i < 4 * 48; i += NT) {   // x_in, k-padded to 48 with zeros
    int c = i / 48, k = i - c * 48;
    L[AB + i] = (k < 45) ? xin[(size_t)b * 180 + c * 45 + k] : 0.f;
  }
  __syncthreads();

  for (int layer = 0; layer < 6; ++layer) {
    const int cin  = (layer == 0) ? 4 : (layer == 1) ? 16 : (layer == 2) ? 32
                   : (layer == 3) ? 64 : (layer == 4) ? 32 : 16;
    const int cout = (layer == 0) ? 16 : (layer == 1) ? 32 : (layer == 2) ? 64
                   : (layer == 3) ? 32 : (layer == 4) ? 16 : 4;
    const float* w = (layer == 0) ? w1c : (layer == 1) ? w2c : (layer == 2) ? w3c
                   : (layer == 3) ? w4c : (layer == 4) ? w5c : w6c;
    const int QB = AB + cin * 48;    // y region
    const int SB = QB + cout * 48;   // sig region (<=32 rows, stride 92)

    // ---- stage 1: sconv  y[o][k] = scale[k] * sum_c x[c][k] * w[o][c][lidx(k)]
    {
      const int items = (cout >> 1) * 12;
      for (int i = tid; i < items; i += NT) {
        const int og = i / 12, kc = i - og * 12;
        const int o0 = og * 2, k0 = kc * 4;
        const int j0 = lidxf(k0), j1 = lidxf(k0 + 1), j2 = lidxf(k0 + 2), j3 = lidxf(k0 + 3);
        const int jl = (j0 < 3) ? j0 : 3;  // per-chunk lidx spans {jl, jl+1}; jl+1 <= 4 in-bounds
        const int s0 = j0 - jl, s1 = j1 - jl, s2 = j2 - jl, s3 = j3 - jl;
        float a0[4] = {0.f, 0.f, 0.f, 0.f}, a1[4] = {0.f, 0.f, 0.f, 0.f};
        const float* wr0 = w + (size_t)o0 * cin * 5 + jl;
        const float* wr1 = wr0 + (size_t)cin * 5;
#pragma unroll 4
        for (int c = 0; c < cin; ++c) {
          const float4 xv = LD4(AB + c * 48 + k0);
          const float wa0 = wr0[0], wa1 = wr0[1];
          const float wb0 = wr1[0], wb1 = wr1[1];
          wr0 += 5; wr1 += 5;
          a0[0] += xv.x * (s0 ? wa1 : wa0);
          a0[1] += xv.y * (s1 ? wa1 : wa0);
          a0[2] += xv.z * (s2 ? wa1 : wa0);
          a0[3] += xv.w * (s3 ? wa1 : wa0);
          a1[0] += xv.x * (s0 ? wb1 : wb0);
          a1[1] += xv.y * (s1 ? wb1 : wb0);
          a1[2] += xv.z * (s2 ? wb1 : wb0);
          a1[3] += xv.w * (s3 ? wb1 : wb0);
        }
        const float sc0 = scale_from_j(j0), sc1 = scale_from_j(j1);
        const float sc2 = scale_from_j(j2), sc3 = scale_from_j(j3);
        // x pad cols are zero -> padded y cols come out zero automatically
        ST4(QB + o0 * 48 + k0, make_float4(a0[0] * sc0, a0[1] * sc1, a0[2] * sc2, a0[3] * sc3));
        ST4(QB + (o0 + 1) * 48 + k0, make_float4(a1[0] * sc0, a1[1] * sc1, a1[2] * sc2, a1[3] * sc3));
      }
    }
    __syncthreads();

    const int halves = (cout + 31) >> 5;
    for (int h = 0; h < halves; ++h) {
      const int h32 = h * 32;
      const int R = (cout - h32 < 32) ? (cout - h32) : 32;

      // ---- stage 2: sig[o][p] = relu( sum_k WI[k][p] * y[o][k] )
      {
        const int items = (R >> 1) * 23;
        for (int i = tid; i < items; i += NT) {
          const int og = i / 23, pg = i - og * 23;
          const int o0 = h32 + og * 2, p0 = pg * 4;
          float a0[4] = {0.f, 0.f, 0.f, 0.f}, a1[4] = {0.f, 0.f, 0.f, 0.f};
          const int yb0 = QB + o0 * 48, yb1 = yb0 + 48;
#pragma unroll
          for (int kc = 0; kc < 11; ++kc) {
            const float4 y0 = LD4(yb0 + kc * 4);
            const float4 y1 = LD4(yb1 + kc * 4);
            const float ya[4] = {y0.x, y0.y, y0.z, y0.w};
            const float yb[4] = {y1.x, y1.y, y1.z, y1.w};
#pragma unroll
            for (int j = 0; j < 4; ++j) {
              const float4 wv = LD4(WIB + (kc * 4 + j) * 92 + p0);
              a0[0] += ya[j] * wv.x; a0[1] += ya[j] * wv.y;
              a0[2] += ya[j] * wv.z; a0[3] += ya[j] * wv.w;
              a1[0] += yb[j] * wv.x; a1[1] += yb[j] * wv.y;
              a1[2] += yb[j] * wv.z; a1[3] += yb[j] * wv.w;
            }
          }
          {  // tail k = 44
            const float ya = L[yb0 + 44], yb = L[yb1 + 44];
            const float4 wv = LD4(WIB + 44 * 92 + p0);
            a0[0] += ya * wv.x; a0[1] += ya * wv.y; a0[2] += ya * wv.z; a0[3] += ya * wv.w;
            a1[0] += yb * wv.x; a1[1] += yb * wv.y; a1[2] += yb * wv.z; a1[3] += yb * wv.w;
          }
          const int sb = SB + (o0 - h32) * 92 + p0;
          ST4(sb, make_float4(fmaxf(a0[0], 0.f), fmaxf(a0[1], 0.f),
                              fmaxf(a0[2], 0.f), fmaxf(a0[3], 0.f)));
          ST4(sb + 92, make_float4(fmaxf(a1[0], 0.f), fmaxf(a1[1], 0.f),
                                   fmaxf(a1[2], 0.f), fmaxf(a1[3], 0.f)));
        }
      }
      __syncthreads();

      // ---- stage 3: x'[o][k] = sum_p WS[p][k] * sig[o][p]   (writes into AB)
      {
        const int items = (R >> 1) * 12;
        for (int i = tid; i < items; i += NT) {
          const int og = i / 12, kc = i - og * 12;
          const int o0 = h32 + og * 2, k0 = kc * 4;
          float a0[4] = {0.f, 0.f, 0.f, 0.f}, a1[4] = {0.f, 0.f, 0.f, 0.f};
          const int sb0 = SB + (o0 - h32) * 92, sb1 = sb0 + 92;
#pragma unroll
          for (int pc = 0; pc < 23; ++pc) {
            const float4 s0 = LD4(sb0 + pc * 4);
            const float4 s1 = LD4(sb1 + pc * 4);
            const float va[4] = {s0.x, s0.y, s0.z, s0.w};
            const float vb[4] = {s1.x, s1.y, s1.z, s1.w};
#pragma unroll
            for (int jp = 0; jp < 4; ++jp) {
              const float4 wv = LD4(WSB + (pc * 4 + jp) * 48 + k0);
              a0[0] += va[jp] * wv.x; a0[1] += va[jp] * wv.y;
              a0[2] += va[jp] * wv.z; a0[3] += va[jp] * wv.w;
              a1[0] += vb[jp] * wv.x; a1[1] += vb[jp] * wv.y;
              a1[2] += vb[jp] * wv.z; a1[3] += vb[jp] * wv.w;
            }
          }
          // WS pad cols k>=45 are zero -> x pad cols stay zero
          ST4(AB + o0 * 48 + k0, make_float4(a0[0], a0[1], a0[2], a0[3]));
          ST4(AB + (o0 + 1) * 48 + k0, make_float4(a1[0], a1[1], a1[2], a1[3]));
        }
      }
      __syncthreads();
    }
  }

  // ---- write final x (4 rows x 45) to out
  for (int i = tid; i < 4 * 45; i += NT) {
    const int c = i / 45, k = i - c * 45;
    out[(size_t)b * 180 + i] = L[AB + c * 48 + k];
  }
}

extern "C" void kernel_launch(void* const* d_in, const int* in_sizes, int n_in,
                              void* d_out, int out_size, void* d_ws, size_t ws_size,
                              hipStream_t stream) {
  (void)n_in; (void)out_size; (void)d_ws; (void)ws_size;
  const float* x    = (const float*)d_in[0];
  const float* sft  = (const float*)d_in[1];
  const float* isft = (const float*)d_in[2];
  const float* w1   = (const float*)d_in[3];
  const float* w2   = (const float*)d_in[4];
  const float* w3   = (const float*)d_in[5];
  const float* w4   = (const float*)d_in[6];
  const float* w5   = (const float*)d_in[7];
  const float* w6   = (const float*)d_in[8];
  float* out = (float*)d_out;
  const int nb = in_sizes[0] / 180;   // 50000
  scnn_all<<<nb, NT, 0, stream>>>(x, sft, isft, w1, w2, w3, w4, w5, w6, out, nb);
}

// Round 2
// 3509.386 us; speedup vs baseline: 1.5996x; 1.5996x over previous
//
#include <hip/hip_runtime.h>

#define NT 256

typedef __attribute__((ext_vector_type(8)))  short bh8;   // 8 bf16 (4 VGPRs)
typedef __attribute__((ext_vector_type(16))) float f16v;  // 32x32 acc
typedef __attribute__((ext_vector_type(4)))  float f4v;   // 16x16 acc

// bf16 round-to-nearest-even split helpers (bit-level; avoids __hip_bfloat16 ABI)
__device__ __forceinline__ unsigned short f2bf(float f) {
  unsigned u = __float_as_uint(f);
  return (unsigned short)((u + 0x7fffu + ((u >> 16) & 1u)) >> 16);
}
__device__ __forceinline__ float bf2f(unsigned short h) {
  return __uint_as_float(((unsigned)h) << 16);
}
__device__ __forceinline__ int lidxf(int k) {  // degree band l/2 for coeff k
  return (k < 1) ? 0 : (k < 6) ? 1 : (k < 15) ? 2 : (k < 28) ? 3 : 4;
}
__device__ __forceinline__ float scale_from_j(int j) {  // sqrt(pi/(4j+1))
  float s = 1.7724539f;
  s = (j == 1) ? 0.79266548f : s;
  s = (j == 2) ? 0.59081795f : s;
  s = (j == 3) ? 0.49159026f : s;
  s = (j >= 4) ? 0.42988324f : s;
  return s;
}

// LDS ushort offsets. WI = isft[p][k] (96 rows, stride 56, zero-padded);
// WS = sft[k'][p] (48 rows, stride 104, zero-padded); B = activation arena:
// y planes [o][k] stride 56 (stage2 B-op) overlaid with s planes [o][p]
// stride 104 (stage3 B-op). Hi/lo split planes for each.
#define WIH 0
#define WIL 5376
#define WSH 10752
#define WSL 15744
#define BH  20736
#define BL  27392
#define NU  34048   // 68096 B; + Xf 12288 B = 80384 B total -> 2 blocks/CU

// stage2 tile: C[m=p][n=o] += sum_k isft[p][k]*y[o][k], 32x32x16 MFMA, K=48
__device__ __forceinline__ f16v s2tile(const unsigned short* U, int mt, int nt,
                                       int llo, int lhi) {
  f16v acc;
#pragma unroll
  for (int e = 0; e < 16; ++e) acc[e] = 0.f;
#pragma unroll
  for (int ks = 0; ks < 3; ++ks) {
    const int ao = (mt * 32 + llo) * 56 + ks * 16 + lhi * 8;
    const bh8 ah = *(const bh8*)&U[WIH + ao];
    const bh8 al = *(const bh8*)&U[WIL + ao];
    const int bo = (nt * 32 + llo) * 56 + ks * 16 + lhi * 8;
    const bh8 bhv = *(const bh8*)&U[BH + bo];
    const bh8 blv = *(const bh8*)&U[BL + bo];
    acc = __builtin_amdgcn_mfma_f32_32x32x16_bf16(ah, bhv, acc, 0, 0, 0);
    acc = __builtin_amdgcn_mfma_f32_32x32x16_bf16(al, bhv, acc, 0, 0, 0);
    acc = __builtin_amdgcn_mfma_f32_32x32x16_bf16(ah, blv, acc, 0, 0, 0);
  }
  return acc;
}

// write relu(C) split hi/lo into s planes [o][p] stride 104.
// C layout (32x32): col=lane&31 (=o), row=(reg&3)+8*(reg>>2)+4*(lane>>5) (=p)
__device__ __forceinline__ void writes_s(unsigned short* U, f16v acc, int mt,
                                         int nt, int llo, int lhi) {
  const int o = nt * 32 + llo;
#pragma unroll
  for (int g = 0; g < 4; ++g) {
    const int p0 = mt * 32 + g * 8 + lhi * 4;
    const float v0 = fmaxf(acc[g * 4 + 0], 0.f);
    const float v1 = fmaxf(acc[g * 4 + 1], 0.f);
    const float v2 = fmaxf(acc[g * 4 + 2], 0.f);
    const float v3 = fmaxf(acc[g * 4 + 3], 0.f);
    const unsigned short h0 = f2bf(v0), h1 = f2bf(v1), h2 = f2bf(v2), h3 = f2bf(v3);
    const unsigned short e0 = f2bf(v0 - bf2f(h0)), e1 = f2bf(v1 - bf2f(h1));
    const unsigned short e2 = f2bf(v2 - bf2f(h2)), e3 = f2bf(v3 - bf2f(h3));
    *(uint2*)&U[BH + o * 104 + p0] =
        make_uint2((unsigned)h0 | ((unsigned)h1 << 16), (unsigned)h2 | ((unsigned)h3 << 16));
    *(uint2*)&U[BL + o * 104 + p0] =
        make_uint2((unsigned)e0 | ((unsigned)e1 << 16), (unsigned)e2 | ((unsigned)e3 << 16));
  }
}

__global__ __launch_bounds__(NT, 2)
void scnn_mfma(const float* __restrict__ xin, const float* __restrict__ sft,
               const float* __restrict__ isft,
               const float* __restrict__ w1, const float* __restrict__ w2,
               const float* __restrict__ w3, const float* __restrict__ w4,
               const float* __restrict__ w5, const float* __restrict__ w6,
               float* __restrict__ out) {
  __shared__ unsigned short U[NU];
  __shared__ float Xf[64 * 48];  // fp32 state [o][k'] stride 48
  const int tid = threadIdx.x;
  const int b = blockIdx.x;
  const int lane = tid & 63;
  const int wv = tid >> 6;           // wave id 0..3
  const int llo = lane & 31, lhi = lane >> 5;
  const int l15 = lane & 15, q4 = lane >> 4;

  // ---- stage static operands (bf16 hi/lo split), zero-padded
  for (int i = tid; i < 96 * 56; i += NT) {
    const int p = i / 56, k = i - p * 56;
    const float v = (p < 90 && k < 45) ? isft[p * 45 + k] : 0.f;
    const unsigned short h = f2bf(v);
    U[WIH + i] = h;
    U[WIL + i] = f2bf(v - bf2f(h));
  }
  for (int i = tid; i < 48 * 104; i += NT) {
    const int kk = i / 104, p = i - kk * 104;
    const float v = (kk < 45 && p < 90) ? sft[kk * 90 + p] : 0.f;
    const unsigned short h = f2bf(v);
    U[WSH + i] = h;
    U[WSL + i] = f2bf(v - bf2f(h));
  }
  for (int i = tid; i < 4 * 48; i += NT) {  // initial x, k-pad 45..47 = 0
    const int c = i / 48, k = i - c * 48;
    Xf[i] = (k < 45) ? xin[(size_t)b * 180 + c * 45 + k] : 0.f;
  }
  __syncthreads();

  for (int layer = 0; layer < 6; ++layer) {
    const int cin  = (layer == 0) ? 4 : (layer == 1) ? 16 : (layer == 2) ? 32
                   : (layer == 3) ? 64 : (layer == 4) ? 32 : 16;
    const int cout = (layer == 0) ? 16 : (layer == 1) ? 32 : (layer == 2) ? 64
                   : (layer == 3) ? 32 : (layer == 4) ? 16 : 4;
    const float* w = (layer == 0) ? w1 : (layer == 1) ? w2 : (layer == 2) ? w3
                   : (layer == 3) ? w4 : (layer == 4) ? w5 : w6;
    const int N32 = (cout + 31) >> 5;   // stage2 n-tiles (32-wide)
    const int N16 = (cout + 15) >> 4;   // stage3 n-tiles (16-wide)
    const int Npad = N32 * 32;

    // ---- (a) sconv (fp32 VALU): y[o][k] -> bf16 hi/lo planes, stride 56.
    // Rows o in [cout, Npad) written as zeros; k pads flow as zeros from Xf.
    {
      const int items = (Npad >> 1) * 12;
      for (int i = tid; i < items; i += NT) {
        const int og = i / 12, kc = i - og * 12;
        const int o0 = og * 2, k0 = kc * 4;
        const int j0 = lidxf(k0), j1 = lidxf(k0 + 1), j2 = lidxf(k0 + 2), j3 = lidxf(k0 + 3);
        const int jl = (j0 < 3) ? j0 : 3;
        const int s0 = j0 - jl, s1 = j1 - jl, s2 = j2 - jl, s3 = j3 - jl;
        const bool r0 = o0 < cout, r1 = (o0 + 1) < cout;
        const float* wr0 = w + (size_t)(r0 ? o0 : 0) * cin * 5 + jl;
        const float* wr1 = w + (size_t)(r1 ? o0 + 1 : 0) * cin * 5 + jl;
        float a00 = 0.f, a01 = 0.f, a02 = 0.f, a03 = 0.f;
        float a10 = 0.f, a11 = 0.f, a12 = 0.f, a13 = 0.f;
#pragma unroll 4
        for (int c = 0; c < cin; ++c) {
          const float4 xv = *(const float4*)&Xf[c * 48 + k0];
          const float wa0 = wr0[0], wa1 = wr0[1];
          const float wb0 = wr1[0], wb1 = wr1[1];
          wr0 += 5; wr1 += 5;
          a00 += xv.x * (s0 ? wa1 : wa0);
          a01 += xv.y * (s1 ? wa1 : wa0);
          a02 += xv.z * (s2 ? wa1 : wa0);
          a03 += xv.w * (s3 ? wa1 : wa0);
          a10 += xv.x * (s0 ? wb1 : wb0);
          a11 += xv.y * (s1 ? wb1 : wb0);
          a12 += xv.z * (s2 ? wb1 : wb0);
          a13 += xv.w * (s3 ? wb1 : wb0);
        }
        const float sc0 = scale_from_j(j0), sc1 = scale_from_j(j1);
        const float sc2 = scale_from_j(j2), sc3 = scale_from_j(j3);
        const float y00 = r0 ? a00 * sc0 : 0.f, y01 = r0 ? a01 * sc1 : 0.f;
        const float y02 = r0 ? a02 * sc2 : 0.f, y03 = r0 ? a03 * sc3 : 0.f;
        const float y10 = r1 ? a10 * sc0 : 0.f, y11 = r1 ? a11 * sc1 : 0.f;
        const float y12 = r1 ? a12 * sc2 : 0.f, y13 = r1 ? a13 * sc3 : 0.f;
        const unsigned short h00 = f2bf(y00), h01 = f2bf(y01), h02 = f2bf(y02), h03 = f2bf(y03);
        const unsigned short h10 = f2bf(y10), h11 = f2bf(y11), h12 = f2bf(y12), h13 = f2bf(y13);
        *(uint2*)&U[BH + o0 * 56 + k0] =
            make_uint2((unsigned)h00 | ((unsigned)h01 << 16), (unsigned)h02 | ((unsigned)h03 << 16));
        *(uint2*)&U[BH + (o0 + 1) * 56 + k0] =
            make_uint2((unsigned)h10 | ((unsigned)h11 << 16), (unsigned)h12 | ((unsigned)h13 << 16));
        const unsigned short g00 = f2bf(y00 - bf2f(h00)), g01 = f2bf(y01 - bf2f(h01));
        const unsigned short g02 = f2bf(y02 - bf2f(h02)), g03 = f2bf(y03 - bf2f(h03));
        const unsigned short g10 = f2bf(y10 - bf2f(h10)), g11 = f2bf(y11 - bf2f(h11));
        const unsigned short g12 = f2bf(y12 - bf2f(h12)), g13 = f2bf(y13 - bf2f(h13));
        *(uint2*)&U[BL + o0 * 56 + k0] =
            make_uint2((unsigned)g00 | ((unsigned)g01 << 16), (unsigned)g02 | ((unsigned)g03 << 16));
        *(uint2*)&U[BL + (o0 + 1) * 56 + k0] =
            make_uint2((unsigned)g10 | ((unsigned)g11 << 16), (unsigned)g12 | ((unsigned)g13 << 16));
      }
    }
    __syncthreads();

    // ---- (b) stage2 MFMA: S^T[p][o] (held in regs across barrier)
    const int T2 = 3 * N32;
    f16v accA, accB;
    const bool hasA = wv < T2, hasB = (wv + 4) < T2;
    if (hasA) accA = s2tile(U, wv % 3, wv / 3, llo, lhi);
    if (hasB) accB = s2tile(U, (wv + 4) % 3, (wv + 4) / 3, llo, lhi);
    __syncthreads();

    // ---- (c) relu + split -> s planes [o][p] stride 104 (overwrites y arena)
    if (hasA) writes_s(U, accA, wv % 3, wv / 3, llo, lhi);
    if (hasB) writes_s(U, accB, (wv + 4) % 3, (wv + 4) / 3, llo, lhi);
    __syncthreads();

    // ---- (d) stage3 MFMA: X'[o][k'] = sum_p sft[k'][p]*s[o][p] -> Xf fp32
    const int T3 = 3 * N16;
    for (int t = wv; t < T3; t += 4) {
      const int nt = t / 3, mt = t - nt * 3;
      f4v acc;
      acc[0] = 0.f; acc[1] = 0.f; acc[2] = 0.f; acc[3] = 0.f;
#pragma unroll
      for (int ks = 0; ks < 3; ++ks) {
        const int ao = (mt * 16 + l15) * 104 + ks * 32 + q4 * 8;
        const bh8 ah = *(const bh8*)&U[WSH + ao];
        const bh8 al = *(const bh8*)&U[WSL + ao];
        const int bo = (nt * 16 + l15) * 104 + ks * 32 + q4 * 8;
        const bh8 bhv = *(const bh8*)&U[BH + bo];
        const bh8 blv = *(const bh8*)&U[BL + bo];
        acc = __builtin_amdgcn_mfma_f32_16x16x32_bf16(ah, bhv, acc, 0, 0, 0);
        acc = __builtin_amdgcn_mfma_f32_16x16x32_bf16(al, bhv, acc, 0, 0, 0);
        acc = __builtin_amdgcn_mfma_f32_16x16x32_bf16(ah, blv, acc, 0, 0, 0);
      }
      // C 16x16: col=lane&15 (=o), row=4*(lane>>4)+reg (=k', consecutive)
      const int o = nt * 16 + l15;
      const int kp = mt * 16 + q4 * 4;
      *(float4*)&Xf[o * 48 + kp] = make_float4(acc[0], acc[1], acc[2], acc[3]);
    }
    __syncthreads();
  }

  // ---- epilogue: out[b][c][k] = Xf[c][k]
  for (int i = tid; i < 180; i += NT) {
    const int c = i / 45, k = i - c * 45;
    out[(size_t)b * 180 + i] = Xf[c * 48 + k];
  }
}

extern "C" void kernel_launch(void* const* d_in, const int* in_sizes, int n_in,
                              void* d_out, int out_size, void* d_ws, size_t ws_size,
                              hipStream_t stream) {
  (void)n_in; (void)out_size; (void)d_ws; (void)ws_size;
  const float* x    = (const float*)d_in[0];
  const float* sft  = (const float*)d_in[1];
  const float* isft = (const float*)d_in[2];
  const float* w1   = (const float*)d_in[3];
  const float* w2   = (const float*)d_in[4];
  const float* w3   = (const float*)d_in[5];
  const float* w4   = (const float*)d_in[6];
  const float* w5   = (const float*)d_in[7];
  const float* w6   = (const float*)d_in[8];
  float* out = (float*)d_out;
  const int nb = in_sizes[0] / 180;  // 50000
  scnn_mfma<<<nb, NT, 0, stream>>>(x, sft, isft, w1, w2, w3, w4, w5, w6, out);
}

// Round 3
// 2113.542 us; speedup vs baseline: 2.6559x; 1.6604x over previous
//
#include <hip/hip_runtime.h>

#define NT 256

typedef __attribute__((ext_vector_type(8)))  short bh8;   // 8 bf16
typedef __attribute__((ext_vector_type(16))) float f16v;  // 32x32 acc
typedef __attribute__((ext_vector_type(4)))  float f4v;   // 16x16 acc

// ---- d_ws layout (ushort units) ----
#define WEH_G 0        // expanded sconv weights, hi plane (28672)
#define WEL_G 28672    // lo plane (28672)
#define WICOPY_G 57344 // WIH|WIL|WSH|WSL contiguous (20736) -> total 78080 ush = 156160 B

// ---- LDS layout (ushort units) ----
#define WIHo 0      // isft[p][k], 96 rows stride 56
#define WILo 5376
#define WSHo 10752  // scale[k']*sft[k'][p], 48 rows stride 104
#define WSLo 15744
#define SHo  20736  // s planes [o][p] stride 104 (6656); overlaid: y planes [o][k] stride 56
#define SLo  27392
#define XHo  34048  // x planes [k][c] stride 72 (3456)
#define XLo  37504
#define NU   40960  // 81920 B -> exactly 2 blocks/CU

__device__ __forceinline__ unsigned short f2bf(float f) {
  unsigned u = __float_as_uint(f);
  return (unsigned short)((u + 0x7fffu + ((u >> 16) & 1u)) >> 16);
}
__device__ __forceinline__ float bf2f(unsigned short h) {
  return __uint_as_float(((unsigned)h) << 16);
}
__device__ __forceinline__ int lidxf(int k) {  // degree band l/2 for coeff k
  return (k < 1) ? 0 : (k < 6) ? 1 : (k < 15) ? 2 : (k < 28) ? 3 : 4;
}
__device__ __forceinline__ float scale_from_j(int j) {  // sqrt(pi/(4j+1))
  float s = 1.7724539f;
  s = (j == 1) ? 0.79266548f : s;
  s = (j == 2) ? 0.59081795f : s;
  s = (j == 3) ? 0.49159026f : s;
  s = (j >= 4) ? 0.42988324f : s;
  return s;
}
__device__ __forceinline__ bh8 zero8() {
  bh8 z;
#pragma unroll
  for (int e = 0; e < 8; ++e) z[e] = 0;
  return z;
}

// ======================= pre-kernel: fill d_ws =======================
__global__ void scnn_prep(const float* __restrict__ sft, const float* __restrict__ isft,
                          const float* __restrict__ w1, const float* __restrict__ w2,
                          const float* __restrict__ w3, const float* __restrict__ w4,
                          const float* __restrict__ w5, const float* __restrict__ w6,
                          unsigned short* __restrict__ wsu) {
  const int gid = blockIdx.x * NT + threadIdx.x;
  const int gstr = gridDim.x * NT;
  const float* wp[6] = {w1, w2, w3, w4, w5, w6};
  const int CIN[6] = {4, 16, 32, 64, 32, 16};
  const int COUT[6] = {16, 32, 64, 32, 16, 4};
  const int CINP[6] = {8, 16, 32, 64, 32, 16};
  const int KP[6] = {64, 96, 160, 320, 160, 96};
  const int R16[6] = {16, 32, 64, 32, 16, 16};
  const int OFF[6] = {0, 1024, 4096, 14336, 24576, 27136};
#pragma unroll
  for (int l = 0; l < 6; ++l) {
    const int cin = CIN[l], cout = COUT[l], cinP = CINP[l], Kp = KP[l];
    const int n = R16[l] * Kp;
    const float* w = wp[l];
    for (int i = gid; i < n; i += gstr) {
      const int o = i / Kp, s = i - o * Kp;
      const int j = s / cinP, c = s - j * cinP;
      float v = 0.f;
      if (o < cout && j < 5 && c < cin) v = w[(o * cin + c) * 5 + j];
      const unsigned short h = f2bf(v);
      wsu[WEH_G + OFF[l] + i] = h;
      wsu[WEL_G + OFF[l] + i] = f2bf(v - bf2f(h));
    }
  }
  for (int i = gid; i < 5376; i += gstr) {  // WI = isft[p][k], stride 56
    const int p = i / 56, k = i - p * 56;
    const float v = (p < 90 && k < 45) ? isft[p * 45 + k] : 0.f;
    const unsigned short h = f2bf(v);
    wsu[WICOPY_G + i] = h;
    wsu[WICOPY_G + 5376 + i] = f2bf(v - bf2f(h));
  }
  for (int i = gid; i < 4992; i += gstr) {  // WS = scale[k']*sft[k'][p], stride 104
    const int kk = i / 104, p = i - kk * 104;
    float v = 0.f;
    if (kk < 45 && p < 90) v = sft[kk * 90 + p] * scale_from_j(lidxf(kk));
    const unsigned short h = f2bf(v);
    wsu[WICOPY_G + 10752 + i] = h;
    wsu[WICOPY_G + 15744 + i] = f2bf(v - bf2f(h));
  }
}

// stage2 tile: C[m=p][n=o] += sum_k WI[p][k]*y[o][k], 32x32x16, K=48
__device__ __forceinline__ f16v s2tile(const unsigned short* U, int mt, int nt,
                                       int llo, int lhi) {
  f16v acc;
#pragma unroll
  for (int e = 0; e < 16; ++e) acc[e] = 0.f;
#pragma unroll
  for (int ks = 0; ks < 3; ++ks) {
    const int ao = (mt * 32 + llo) * 56 + ks * 16 + lhi * 8;
    const bh8 ah = *(const bh8*)&U[WIHo + ao];
    const bh8 al = *(const bh8*)&U[WILo + ao];
    const int bo = (nt * 32 + llo) * 56 + ks * 16 + lhi * 8;
    const bh8 bhv = *(const bh8*)&U[SHo + bo];  // y overlay
    const bh8 blv = *(const bh8*)&U[SLo + bo];
    acc = __builtin_amdgcn_mfma_f32_32x32x16_bf16(ah, bhv, acc, 0, 0, 0);
    acc = __builtin_amdgcn_mfma_f32_32x32x16_bf16(al, bhv, acc, 0, 0, 0);
    acc = __builtin_amdgcn_mfma_f32_32x32x16_bf16(ah, blv, acc, 0, 0, 0);
  }
  return acc;
}

// write relu(C) split hi/lo into s planes [o][p] stride 104
__device__ __forceinline__ void writes_s(unsigned short* U, f16v acc, int mt,
                                         int nt, int llo, int lhi) {
  const int o = nt * 32 + llo;
#pragma unroll
  for (int g = 0; g < 4; ++g) {
    const int p0 = mt * 32 + g * 8 + lhi * 4;
    const float v0 = fmaxf(acc[g * 4 + 0], 0.f);
    const float v1 = fmaxf(acc[g * 4 + 1], 0.f);
    const float v2 = fmaxf(acc[g * 4 + 2], 0.f);
    const float v3 = fmaxf(acc[g * 4 + 3], 0.f);
    const unsigned short h0 = f2bf(v0), h1 = f2bf(v1), h2 = f2bf(v2), h3 = f2bf(v3);
    const unsigned short e0 = f2bf(v0 - bf2f(h0)), e1 = f2bf(v1 - bf2f(h1));
    const unsigned short e2 = f2bf(v2 - bf2f(h2)), e3 = f2bf(v3 - bf2f(h3));
    *(uint2*)&U[SHo + o * 104 + p0] =
        make_uint2((unsigned)h0 | ((unsigned)h1 << 16), (unsigned)h2 | ((unsigned)h3 << 16));
    *(uint2*)&U[SLo + o * 104 + p0] =
        make_uint2((unsigned)e0 | ((unsigned)e1 << 16), (unsigned)e2 | ((unsigned)e3 << 16));
  }
}

// ======================= main kernel =======================
__global__ __launch_bounds__(NT, 2)
void scnn_main(const float* __restrict__ xin, const unsigned short* __restrict__ wsu,
               float* __restrict__ out) {
  __shared__ __align__(16) unsigned short U[NU];
  const int tid = threadIdx.x, b = blockIdx.x;
  const int lane = tid & 63, wv = tid >> 6;
  const int llo = lane & 31, lhi = lane >> 5;
  const int l15 = lane & 15, q4 = lane >> 4;

  // ---- stage WI/WS planes: straight contiguous copy from ws (41472 B)
  for (int i = tid; i < 2592; i += NT)
    *(uint4*)&U[i * 8] = *(const uint4*)&wsu[WICOPY_G + i * 8];
  // ---- stage initial X: [k][c] stride 72, cols 0..7 (cin=4 + zero pad), scale-folded
  for (int i = tid; i < 384; i += NT) {
    const int k = i >> 3, c = i & 7;
    float v = 0.f;
    if (c < 4 && k < 45) v = xin[(size_t)b * 180 + c * 45 + k] * scale_from_j(lidxf(k));
    const unsigned short h = f2bf(v);
    U[XHo + k * 72 + c] = h;
    U[XLo + k * 72 + c] = f2bf(v - bf2f(h));
  }
  __syncthreads();

  for (int layer = 0; layer < 6; ++layer) {
    const int lg   = (layer == 0) ? 3 : (layer == 1) ? 4 : (layer == 2) ? 5
                   : (layer == 3) ? 6 : (layer == 4) ? 5 : 4;  // log2(cinP)
    const int cinP = 1 << lg;
    const int Kp   = (layer == 0) ? 64 : (layer == 1) ? 96 : (layer == 2) ? 160
                   : (layer == 3) ? 320 : (layer == 4) ? 160 : 96;
    const int weoff= (layer == 0) ? 0 : (layer == 1) ? 1024 : (layer == 2) ? 4096
                   : (layer == 3) ? 14336 : (layer == 4) ? 24576 : 27136;
    const int nt16 = (layer == 2) ? 4 : (layer == 1 || layer == 3) ? 2 : 1;
    const int n32  = (layer == 2) ? 2 : 1;

    // ---- (a) sconv via MFMA with on-the-fly K-expanded A-frags.
    //      C[m=k][n=o] = sum_s X[k][s-band]*we[o][s]; epilogue splits y into
    //      hi/lo planes [o][k] stride 56 (the stage2 B operand).
    {
      const int T = 3 * nt16;
      const int hi5 = (5 * cinP + 31) >> 5;
      const int hi4 = (4 * cinP + 31) >> 5;
      const int lo3 = (3 * cinP) >> 5;
      const int lo4 = cinP >> 3;
      for (int t = wv; t < T; t += 4) {
        const int mt = t % 3, nt = t / 3;
        const int k = mt * 16 + l15;
        const int jb = lidxf(k) << lg;
        const int lo = (mt == 0) ? 0 : (mt == 1) ? lo3 : lo4;
        const int hi = (mt == 0) ? hi4 : hi5;
        const unsigned short* wbh = wsu + WEH_G + weoff + (nt * 16 + l15) * Kp + q4 * 8;
        const unsigned short* wbl = wsu + WEL_G + weoff + (nt * 16 + l15) * Kp + q4 * 8;
        f4v acc;
        acc[0] = 0.f; acc[1] = 0.f; acc[2] = 0.f; acc[3] = 0.f;
        for (int st = lo; st < hi; ++st) {
          const int S = st * 32 + q4 * 8;
          const unsigned c0 = (unsigned)(S - jb);
          const int cs = (int)(c0 & 56u);
          bh8 xh = *(const bh8*)&U[XHo + k * 72 + cs];
          bh8 xl = *(const bh8*)&U[XLo + k * 72 + cs];
          if (c0 >= (unsigned)cinP) { xh = zero8(); xl = zero8(); }
          const bh8 wh = *(const bh8*)&wbh[st * 32];
          const bh8 wl = *(const bh8*)&wbl[st * 32];
          acc = __builtin_amdgcn_mfma_f32_16x16x32_bf16(xh, wh, acc, 0, 0, 0);
          acc = __builtin_amdgcn_mfma_f32_16x16x32_bf16(xl, wh, acc, 0, 0, 0);
          acc = __builtin_amdgcn_mfma_f32_16x16x32_bf16(xh, wl, acc, 0, 0, 0);
        }
        // epilogue: lane holds y[o][kq..kq+3] (C: col=o, rows consecutive k)
        const int o = nt * 16 + l15;
        const int kq = mt * 16 + q4 * 4;
        const unsigned short h0 = f2bf(acc[0]), h1 = f2bf(acc[1]);
        const unsigned short h2 = f2bf(acc[2]), h3 = f2bf(acc[3]);
        const unsigned short g0 = f2bf(acc[0] - bf2f(h0)), g1 = f2bf(acc[1] - bf2f(h1));
        const unsigned short g2 = f2bf(acc[2] - bf2f(h2)), g3 = f2bf(acc[3] - bf2f(h3));
        *(uint2*)&U[SHo + o * 56 + kq] =
            make_uint2((unsigned)h0 | ((unsigned)h1 << 16), (unsigned)h2 | ((unsigned)h3 << 16));
        *(uint2*)&U[SLo + o * 56 + kq] =
            make_uint2((unsigned)g0 | ((unsigned)g1 << 16), (unsigned)g2 | ((unsigned)g3 << 16));
      }
      if (16 * nt16 < 32 * n32) {  // zero y rows [16,32) (layers 0,4,5)
        for (int i = tid; i < 448; i += NT) {
          const int pl = (i >= 224) ? 1 : 0;
          const int ii = i - pl * 224;
          const int r = 16 + ii / 14;
          const int c4 = (ii - (r - 16) * 14) * 4;
          *(uint2*)&U[(pl ? SLo : SHo) + r * 56 + c4] = make_uint2(0u, 0u);
        }
      }
    }
    __syncthreads();

    // ---- (b) stage2 MFMA (held in regs across barrier)
    const int T2 = 3 * n32;
    f16v accA, accB;
    const bool hasA = wv < T2, hasB = (wv + 4) < T2;
    if (hasA) accA = s2tile(U, wv % 3, wv / 3, llo, lhi);
    if (hasB) accB = s2tile(U, (wv + 4) % 3, (wv + 4) / 3, llo, lhi);
    __syncthreads();

    // ---- (c) relu + split -> s planes [o][p] stride 104 (overwrites y arena)
    if (hasA) writes_s(U, accA, wv % 3, wv / 3, llo, lhi);
    if (hasB) writes_s(U, accB, (wv + 4) % 3, (wv + 4) / 3, llo, lhi);
    __syncthreads();

    // ---- (d) stage3 MFMA: x'[k'][o] = sum_p WS'[k'][p]*s[o][p]; epilogue
    //      splits into X planes [k][c] stride 72 (next layer's sconv A operand)
    const int T3 = 3 * nt16;
    for (int t = wv; t < T3; t += 4) {
      const int nt = t / 3, mt = t - nt * 3;
      f4v acc;
      acc[0] = 0.f; acc[1] = 0.f; acc[2] = 0.f; acc[3] = 0.f;
#pragma unroll
      for (int ks = 0; ks < 3; ++ks) {
        const int ao = (mt * 16 + l15) * 104 + ks * 32 + q4 * 8;
        const bh8 ah = *(const bh8*)&U[WSHo + ao];
        const bh8 al = *(const bh8*)&U[WSLo + ao];
        const int bo = (nt * 16 + l15) * 104 + ks * 32 + q4 * 8;
        const bh8 bhv = *(const bh8*)&U[SHo + bo];
        const bh8 blv = *(const bh8*)&U[SLo + bo];
        acc = __builtin_amdgcn_mfma_f32_16x16x32_bf16(ah, bhv, acc, 0, 0, 0);
        acc = __builtin_amdgcn_mfma_f32_16x16x32_bf16(al, bhv, acc, 0, 0, 0);
        acc = __builtin_amdgcn_mfma_f32_16x16x32_bf16(ah, blv, acc, 0, 0, 0);
      }
      const int o = nt * 16 + l15;
      const int kp = mt * 16 + q4 * 4;
#pragma unroll
      for (int r = 0; r < 4; ++r) {
        const float v = acc[r];
        const unsigned short h = f2bf(v);
        U[XHo + (kp + r) * 72 + o] = h;
        U[XLo + (kp + r) * 72 + o] = f2bf(v - bf2f(h));
      }
    }
    __syncthreads();
  }

  // ---- epilogue: out[b][c][k] = (XH+XL)[k][c] / scale[k]  (undo scale fold)
  for (int i = tid; i < 180; i += NT) {
    const int c = i / 45, k = i - c * 45;
    const float v = bf2f(U[XHo + k * 72 + c]) + bf2f(U[XLo + k * 72 + c]);
    out[(size_t)b * 180 + i] = v / scale_from_j(lidxf(k));
  }
}

extern "C" void kernel_launch(void* const* d_in, const int* in_sizes, int n_in,
                              void* d_out, int out_size, void* d_ws, size_t ws_size,
                              hipStream_t stream) {
  (void)n_in; (void)out_size; (void)ws_size;
  const float* x    = (const float*)d_in[0];
  const float* sft  = (const float*)d_in[1];
  const float* isft = (const float*)d_in[2];
  const float* w1   = (const float*)d_in[3];
  const float* w2   = (const float*)d_in[4];
  const float* w3   = (const float*)d_in[5];
  const float* w4   = (const float*)d_in[6];
  const float* w5   = (const float*)d_in[7];
  const float* w6   = (const float*)d_in[8];
  float* out = (float*)d_out;
  unsigned short* wsu = (unsigned short*)d_ws;  // uses 156160 B of scratch
  const int nb = in_sizes[0] / 180;             // 50000
  scnn_prep<<<32, NT, 0, stream>>>(sft, isft, w1, w2, w3, w4, w5, w6, wsu);
  scnn_main<<<nb, NT, 0, stream>>>(x, wsu, out);
}

// Round 4
// 1614.492 us; speedup vs baseline: 3.4769x; 1.3091x over previous
//
#include <hip/hip_runtime.h>

#define NT 256

typedef __attribute__((ext_vector_type(8)))  short bh8;   // 8 bf16
typedef __attribute__((ext_vector_type(16))) float f16v;  // 32x32 acc
typedef __attribute__((ext_vector_type(4)))  float f4v;   // 16x16 acc

// ---- d_ws layout (ushort units) ----
#define WEH_G 0        // expanded sconv weights, hi plane (28672)
#define WEL_G 28672    // lo plane (28672)
#define G_WIH 57344    // isft[p][k], 96 rows stride 56 (5376)
#define G_WIL 62720
#define G_WSH 68096    // scale[k']*sft[k'][p], 48 rows stride 104 (4992)
#define G_WSL 73088    // total 78080 ush = 156160 B

// ---- LDS layout (ushort units): activations only ----
#define SHo  0      // s planes [o][p] stride 104 (6656); overlay: y planes [o][k] stride 56
#define SLo  6656
#define XHo  13312  // x planes [k][c] stride 72 (3456)
#define XLo  16768
#define NU   20224  // 40448 B -> 4 blocks/CU (161792 <= 163840)

__device__ __forceinline__ unsigned short f2bf(float f) {  // RNE
  unsigned u = __float_as_uint(f);
  return (unsigned short)((u + 0x7fffu + ((u >> 16) & 1u)) >> 16);
}
__device__ __forceinline__ unsigned short f2bf_t(float f) {  // truncate
  return (unsigned short)(__float_as_uint(f) >> 16);
}
__device__ __forceinline__ float bf2f(unsigned short h) {
  return __uint_as_float(((unsigned)h) << 16);
}
__device__ __forceinline__ int lidxf(int k) {  // degree band l/2 for coeff k
  return (k < 1) ? 0 : (k < 6) ? 1 : (k < 15) ? 2 : (k < 28) ? 3 : 4;
}
__device__ __forceinline__ float scale_from_j(int j) {  // sqrt(pi/(4j+1))
  float s = 1.7724539f;
  s = (j == 1) ? 0.79266548f : s;
  s = (j == 2) ? 0.59081795f : s;
  s = (j == 3) ? 0.49159026f : s;
  s = (j >= 4) ? 0.42988324f : s;
  return s;
}
__device__ __forceinline__ bh8 zero8() {
  bh8 z;
#pragma unroll
  for (int e = 0; e < 8; ++e) z[e] = 0;
  return z;
}

// ======================= pre-kernel: fill d_ws =======================
__global__ void scnn_prep(const float* __restrict__ sft, const float* __restrict__ isft,
                          const float* __restrict__ w1, const float* __restrict__ w2,
                          const float* __restrict__ w3, const float* __restrict__ w4,
                          const float* __restrict__ w5, const float* __restrict__ w6,
                          unsigned short* __restrict__ wsu) {
  const int gid = blockIdx.x * NT + threadIdx.x;
  const int gstr = gridDim.x * NT;
  const float* wp[6] = {w1, w2, w3, w4, w5, w6};
  const int CIN[6] = {4, 16, 32, 64, 32, 16};
  const int COUT[6] = {16, 32, 64, 32, 16, 4};
  const int CINP[6] = {8, 16, 32, 64, 32, 16};
  const int KP[6] = {64, 96, 160, 320, 160, 96};
  const int R16[6] = {16, 32, 64, 32, 16, 16};
  const int OFF[6] = {0, 1024, 4096, 14336, 24576, 27136};
#pragma unroll
  for (int l = 0; l < 6; ++l) {
    const int cin = CIN[l], cout = COUT[l], cinP = CINP[l], Kp = KP[l];
    const int n = R16[l] * Kp;
    const float* w = wp[l];
    for (int i = gid; i < n; i += gstr) {
      const int o = i / Kp, s = i - o * Kp;
      const int j = s / cinP, c = s - j * cinP;
      float v = 0.f;
      if (o < cout && j < 5 && c < cin) v = w[(o * cin + c) * 5 + j];
      const unsigned short h = f2bf(v);
      wsu[WEH_G + OFF[l] + i] = h;
      wsu[WEL_G + OFF[l] + i] = f2bf(v - bf2f(h));
    }
  }
  for (int i = gid; i < 5376; i += gstr) {  // WI = isft[p][k], stride 56
    const int p = i / 56, k = i - p * 56;
    const float v = (p < 90 && k < 45) ? isft[p * 45 + k] : 0.f;
    const unsigned short h = f2bf(v);
    wsu[G_WIH + i] = h;
    wsu[G_WIL + i] = f2bf(v - bf2f(h));
  }
  for (int i = gid; i < 4992; i += gstr) {  // WS = scale[k']*sft[k'][p], stride 104
    const int kk = i / 104, p = i - kk * 104;
    float v = 0.f;
    if (kk < 45 && p < 90) v = sft[kk * 90 + p] * scale_from_j(lidxf(kk));
    const unsigned short h = f2bf(v);
    wsu[G_WSH + i] = h;
    wsu[G_WSL + i] = f2bf(v - bf2f(h));
  }
}

// stage2 tile: C[m=p][n=o] += sum_k WI[p][k]*y[o][k], 32x32x16, K=48.
// A-frags straight from global (L1/L2-resident); B-frags (y) from LDS.
__device__ __forceinline__ f16v s2tile(const unsigned short* U,
                                       const unsigned short* __restrict__ wsu,
                                       int mt, int nt, int llo, int lhi) {
  f16v acc;
#pragma unroll
  for (int e = 0; e < 16; ++e) acc[e] = 0.f;
#pragma unroll
  for (int ks = 0; ks < 3; ++ks) {
    const int ao = (mt * 32 + llo) * 56 + ks * 16 + lhi * 8;
    const bh8 ah = *(const bh8*)&wsu[G_WIH + ao];
    const bh8 al = *(const bh8*)&wsu[G_WIL + ao];
    const int bo = (nt * 32 + llo) * 56 + ks * 16 + lhi * 8;
    const bh8 bhv = *(const bh8*)&U[SHo + bo];  // y overlay
    const bh8 blv = *(const bh8*)&U[SLo + bo];
    acc = __builtin_amdgcn_mfma_f32_32x32x16_bf16(ah, bhv, acc, 0, 0, 0);
    acc = __builtin_amdgcn_mfma_f32_32x32x16_bf16(al, bhv, acc, 0, 0, 0);
    acc = __builtin_amdgcn_mfma_f32_32x32x16_bf16(ah, blv, acc, 0, 0, 0);
  }
  return acc;
}

// write relu(C) split hi/lo into s planes [o][p] stride 104
__device__ __forceinline__ void writes_s(unsigned short* U, f16v acc, int mt,
                                         int nt, int llo, int lhi) {
  const int o = nt * 32 + llo;
#pragma unroll
  for (int g = 0; g < 4; ++g) {
    const int p0 = mt * 32 + g * 8 + lhi * 4;
    const float v0 = fmaxf(acc[g * 4 + 0], 0.f);
    const float v1 = fmaxf(acc[g * 4 + 1], 0.f);
    const float v2 = fmaxf(acc[g * 4 + 2], 0.f);
    const float v3 = fmaxf(acc[g * 4 + 3], 0.f);
    const unsigned short h0 = f2bf_t(v0), h1 = f2bf_t(v1), h2 = f2bf_t(v2), h3 = f2bf_t(v3);
    const unsigned short e0 = f2bf(v0 - bf2f(h0)), e1 = f2bf(v1 - bf2f(h1));
    const unsigned short e2 = f2bf(v2 - bf2f(h2)), e3 = f2bf(v3 - bf2f(h3));
    *(uint2*)&U[SHo + o * 104 + p0] =
        make_uint2((unsigned)h0 | ((unsigned)h1 << 16), (unsigned)h2 | ((unsigned)h3 << 16));
    *(uint2*)&U[SLo + o * 104 + p0] =
        make_uint2((unsigned)e0 | ((unsigned)e1 << 16), (unsigned)e2 | ((unsigned)e3 << 16));
  }
}

// ======================= main kernel =======================
__global__ __launch_bounds__(NT, 4)
void scnn_main(const float* __restrict__ xin, const unsigned short* __restrict__ wsu,
               float* __restrict__ out) {
  __shared__ __align__(16) unsigned short U[NU];
  const int tid = threadIdx.x, b = blockIdx.x;
  const int lane = tid & 63, wv = tid >> 6;
  const int llo = lane & 31, lhi = lane >> 5;
  const int l15 = lane & 15, q4 = lane >> 4;

  // ---- stage initial X: [k][c] stride 72, cols 0..7 (cin=4 + zero pad), scale-folded
  for (int i = tid; i < 384; i += NT) {
    const int k = i >> 3, c = i & 7;
    float v = 0.f;
    if (c < 4 && k < 45) v = xin[(size_t)b * 180 + c * 45 + k] * scale_from_j(lidxf(k));
    const unsigned short h = f2bf_t(v);
    U[XHo + k * 72 + c] = h;
    U[XLo + k * 72 + c] = f2bf(v - bf2f(h));
  }
  __syncthreads();

  for (int layer = 0; layer < 6; ++layer) {
    const int lg   = (layer == 0) ? 3 : (layer == 1) ? 4 : (layer == 2) ? 5
                   : (layer == 3) ? 6 : (layer == 4) ? 5 : 4;  // log2(cinP)
    const int cinP = 1 << lg;
    const int Kp   = (layer == 0) ? 64 : (layer == 1) ? 96 : (layer == 2) ? 160
                   : (layer == 3) ? 320 : (layer == 4) ? 160 : 96;
    const int weoff= (layer == 0) ? 0 : (layer == 1) ? 1024 : (layer == 2) ? 4096
                   : (layer == 3) ? 14336 : (layer == 4) ? 24576 : 27136;
    const int nt16 = (layer == 2) ? 4 : (layer == 1 || layer == 3) ? 2 : 1;
    const int n32  = (layer == 2) ? 2 : 1;

    // ---- (a) sconv via MFMA with on-the-fly K-expanded A-frags.
    {
      const int T = 3 * nt16;
      const int hi5 = (5 * cinP + 31) >> 5;
      const int hi4 = (4 * cinP + 31) >> 5;
      const int lo3 = (3 * cinP) >> 5;
      const int lo4 = cinP >> 3;
      for (int t = wv; t < T; t += 4) {
        const int mt = t % 3, nt = t / 3;
        const int k = mt * 16 + l15;
        const int jb = lidxf(k) << lg;
        const int lo = (mt == 0) ? 0 : (mt == 1) ? lo3 : lo4;
        const int hi = (mt == 0) ? hi4 : hi5;
        const unsigned short* wbh = wsu + WEH_G + weoff + (nt * 16 + l15) * Kp + q4 * 8;
        const unsigned short* wbl = wsu + WEL_G + weoff + (nt * 16 + l15) * Kp + q4 * 8;
        f4v acc;
        acc[0] = 0.f; acc[1] = 0.f; acc[2] = 0.f; acc[3] = 0.f;
        for (int st = lo; st < hi; ++st) {
          const int S = st * 32 + q4 * 8;
          const unsigned c0 = (unsigned)(S - jb);
          const int cs = (int)(c0 & 56u);
          bh8 xh = *(const bh8*)&U[XHo + k * 72 + cs];
          bh8 xl = *(const bh8*)&U[XLo + k * 72 + cs];
          if (c0 >= (unsigned)cinP) { xh = zero8(); xl = zero8(); }
          const bh8 wh = *(const bh8*)&wbh[st * 32];
          const bh8 wl = *(const bh8*)&wbl[st * 32];
          acc = __builtin_amdgcn_mfma_f32_16x16x32_bf16(xh, wh, acc, 0, 0, 0);
          acc = __builtin_amdgcn_mfma_f32_16x16x32_bf16(xl, wh, acc, 0, 0, 0);
          acc = __builtin_amdgcn_mfma_f32_16x16x32_bf16(xh, wl, acc, 0, 0, 0);
        }
        // epilogue: lane holds y[o][kq..kq+3] (C: col=o, rows consecutive k)
        const int o = nt * 16 + l15;
        const int kq = mt * 16 + q4 * 4;
        const unsigned short h0 = f2bf_t(acc[0]), h1 = f2bf_t(acc[1]);
        const unsigned short h2 = f2bf_t(acc[2]), h3 = f2bf_t(acc[3]);
        const unsigned short g0 = f2bf(acc[0] - bf2f(h0)), g1 = f2bf(acc[1] - bf2f(h1));
        const unsigned short g2 = f2bf(acc[2] - bf2f(h2)), g3 = f2bf(acc[3] - bf2f(h3));
        *(uint2*)&U[SHo + o * 56 + kq] =
            make_uint2((unsigned)h0 | ((unsigned)h1 << 16), (unsigned)h2 | ((unsigned)h3 << 16));
        *(uint2*)&U[SLo + o * 56 + kq] =
            make_uint2((unsigned)g0 | ((unsigned)g1 << 16), (unsigned)g2 | ((unsigned)g3 << 16));
      }
      if (16 * nt16 < 32 * n32) {  // zero y rows [16,32) (layers 0,4,5)
        for (int i = tid; i < 448; i += NT) {
          const int pl = (i >= 224) ? 1 : 0;
          const int ii = i - pl * 224;
          const int r = 16 + ii / 14;
          const int c4 = (ii - (r - 16) * 14) * 4;
          *(uint2*)&U[(pl ? SLo : SHo) + r * 56 + c4] = make_uint2(0u, 0u);
        }
      }
    }
    __syncthreads();

    // ---- (b) stage2 MFMA (held in regs across barrier)
    const int T2 = 3 * n32;
    f16v accA, accB;
    const bool hasA = wv < T2, hasB = (wv + 4) < T2;
    if (hasA) accA = s2tile(U, wsu, wv % 3, wv / 3, llo, lhi);
    if (hasB) accB = s2tile(U, wsu, (wv + 4) % 3, (wv + 4) / 3, llo, lhi);
    __syncthreads();

    // ---- (c) relu + split -> s planes [o][p] stride 104 (overwrites y arena)
    if (hasA) writes_s(U, accA, wv % 3, wv / 3, llo, lhi);
    if (hasB) writes_s(U, accB, (wv + 4) % 3, (wv + 4) / 3, llo, lhi);
    __syncthreads();

    // ---- (d) stage3 MFMA: x'[k'][o] = sum_p WS'[k'][p]*s[o][p]; A from global
    const int T3 = 3 * nt16;
    for (int t = wv; t < T3; t += 4) {
      const int nt = t / 3, mt = t - nt * 3;
      f4v acc;
      acc[0] = 0.f; acc[1] = 0.f; acc[2] = 0.f; acc[3] = 0.f;
#pragma unroll
      for (int ks = 0; ks < 3; ++ks) {
        const int ao = (mt * 16 + l15) * 104 + ks * 32 + q4 * 8;
        const bh8 ah = *(const bh8*)&wsu[G_WSH + ao];
        const bh8 al = *(const bh8*)&wsu[G_WSL + ao];
        const int bo = (nt * 16 + l15) * 104 + ks * 32 + q4 * 8;
        const bh8 bhv = *(const bh8*)&U[SHo + bo];
        const bh8 blv = *(const bh8*)&U[SLo + bo];
        acc = __builtin_amdgcn_mfma_f32_16x16x32_bf16(ah, bhv, acc, 0, 0, 0);
        acc = __builtin_amdgcn_mfma_f32_16x16x32_bf16(al, bhv, acc, 0, 0, 0);
        acc = __builtin_amdgcn_mfma_f32_16x16x32_bf16(ah, blv, acc, 0, 0, 0);
      }
      const int o = nt * 16 + l15;
      const int kp = mt * 16 + q4 * 4;
#pragma unroll
      for (int r = 0; r < 4; ++r) {
        const float v = acc[r];
        const unsigned short h = f2bf_t(v);
        U[XHo + (kp + r) * 72 + o] = h;
        U[XLo + (kp + r) * 72 + o] = f2bf(v - bf2f(h));
      }
    }
    __syncthreads();
  }

  // ---- epilogue: out[b][c][k] = (XH+XL)[k][c] / scale[k]  (undo scale fold)
  for (int i = tid; i < 180; i += NT) {
    const int c = i / 45, k = i - c * 45;
    const float v = bf2f(U[XHo + k * 72 + c]) + bf2f(U[XLo + k * 72 + c]);
    out[(size_t)b * 180 + i] = v / scale_from_j(lidxf(k));
  }
}

extern "C" void kernel_launch(void* const* d_in, const int* in_sizes, int n_in,
                              void* d_out, int out_size, void* d_ws, size_t ws_size,
                              hipStream_t stream) {
  (void)n_in; (void)out_size; (void)ws_size;
  const float* x    = (const float*)d_in[0];
  const float* sft  = (const float*)d_in[1];
  const float* isft = (const float*)d_in[2];
  const float* w1   = (const float*)d_in[3];
  const float* w2   = (const float*)d_in[4];
  const float* w3   = (const float*)d_in[5];
  const float* w4   = (const float*)d_in[6];
  const float* w5   = (const float*)d_in[7];
  const float* w6   = (const float*)d_in[8];
  float* out = (float*)d_out;
  unsigned short* wsu = (unsigned short*)d_ws;  // uses 156160 B of scratch
  const int nb = in_sizes[0] / 180;             // 50000
  scnn_prep<<<32, NT, 0, stream>>>(sft, isft, w1, w2, w3, w4, w5, w6, wsu);
  scnn_main<<<nb, NT, 0, stream>>>(x, wsu, out);
}